// Round 1
// baseline (771.427 us; speedup 1.0000x reference)
//
#include <hip/hip_runtime.h>

// Problem constants
#define BB   2
#define DD   64
#define RR   256
#define EE   37
#define AA   107
#define REA  (EE*AA)        // 3959
#define SLOTS 4096
#define SPT   16            // slots per thread (4096/256)
#define KTOP  100
#define FEAT_N (BB*RR*KTOP*4)   // 204800 floats, then coords after

__global__ __launch_bounds__(256, 2)
void radar_topk_kernel(const float* __restrict__ in, float* __restrict__ out) {
    __shared__ unsigned long long keys[SLOTS];
    __shared__ unsigned long long warr[4];
    __shared__ unsigned long long winners[KTOP];

    const int t   = threadIdx.x;
    const int blk = blockIdx.x;     // [0, 512)
    const int b   = blk >> 8;
    const int r   = blk & 255;

    // ---- phase 1: mean over doppler, sequential in d (match reference FP order) ----
    float acc[SPT];
    #pragma unroll
    for (int s = 0; s < SPT; ++s) acc[s] = 0.0f;

    // offset(b,d,r,rea) = ((b*DD + d)*RR + r)*REA + rea
    const float* p0 = in + ((size_t)b * DD * RR + r) * (size_t)REA;
    const size_t dstride = (size_t)RR * REA;

    for (int d = 0; d < DD; ++d) {
        const float* pd = p0 + (size_t)d * dstride;
        #pragma unroll
        for (int s = 0; s < SPT; ++s) {
            int rea = t + (s << 8);
            if (rea < REA) acc[s] += pd[rea];
        }
    }

    // ---- build 64-bit sort keys: (flipped f32) << 32 | ~rea ----
    #pragma unroll
    for (int s = 0; s < SPT; ++s) {
        int rea = t + (s << 8);
        unsigned long long key = 0ull;
        if (rea < REA) {
            float v = acc[s] * 0.015625f;            // /64 (exact)
            unsigned u = __float_as_uint(v);
            u ^= (u & 0x80000000u) ? 0xFFFFFFFFu : 0x80000000u;  // monotonic flip
            key = ((unsigned long long)u << 32) | (unsigned)(~rea);
        }
        keys[rea] = key;     // rea covers [0,4096) exactly; pads get key=0
    }
    __syncthreads();

    // ---- phase 2: iterative top-100 (block argmax, clear, repeat) ----
    for (int k = 0; k < KTOP; ++k) {
        unsigned long long m = 0ull;
        #pragma unroll
        for (int s = 0; s < SPT; ++s) {
            unsigned long long kk = keys[t + (s << 8)];
            m = (kk > m) ? kk : m;
        }
        #pragma unroll
        for (int off = 32; off > 0; off >>= 1) {
            unsigned long long o = __shfl_xor(m, off);
            m = (o > m) ? o : m;
        }
        if ((t & 63) == 0) warr[t >> 6] = m;
        __syncthreads();
        if (t == 0) {
            unsigned long long w0 = warr[0], w1 = warr[1];
            unsigned long long w2 = warr[2], w3 = warr[3];
            unsigned long long w = (w0 > w1) ? w0 : w1;
            unsigned long long x = (w2 > w3) ? w2 : w3;
            w = (w > x) ? w : x;
            winners[k] = w;
            int rea = (int)(~(unsigned)w);   // decode index
            keys[rea] = 0ull;                // remove from candidates
        }
        __syncthreads();
    }

    // ---- phase 3: emit features + coords (both stored as f32 values) ----
    if (t < KTOP) {
        unsigned long long w = winners[t];
        unsigned u = (unsigned)(w >> 32);
        u ^= (u & 0x80000000u) ? 0x80000000u : 0xFFFFFFFFu;  // un-flip
        float val = __uint_as_float(u);
        int rea  = (int)(~(unsigned)w);
        int elev = rea / AA;
        int azim = rea - elev * AA;
        int row  = (b * RR + r) * KTOP + t;

        float4 f = make_float4((float)azim, (float)r, (float)elev, val);
        *(float4*)(out + (size_t)row * 4) = f;
        float4 c = make_float4((float)b, (float)(elev + 1), (float)r, (float)(azim + 74));
        *(float4*)(out + FEAT_N + (size_t)row * 4) = c;
    }
}

extern "C" void kernel_launch(void* const* d_in, const int* in_sizes, int n_in,
                              void* d_out, int out_size, void* d_ws, size_t ws_size,
                              hipStream_t stream) {
    const float* in = (const float*)d_in[0];
    float* out = (float*)d_out;
    radar_topk_kernel<<<dim3(BB * RR), dim3(256), 0, stream>>>(in, out);
}